// Round 1
// baseline (398.401 us; speedup 1.0000x reference)
//
#include <hip/hip_runtime.h>

// HeteroGraphAttentionLayer: B=8, S=2048, E=1024, H=4, D=256
// Pipeline: cast->bf16 | GEMM1 (x@W_lin^T+b) | per-head QKV (V transposed) |
//           flash attention | per-head out_proj -> fp32 d_out.
// Scratch: d_out lower/upper halves hold xb / x_proj (dead before final write);
//          K reuses xb region. d_ws: Q(32M) Vt(32M) AO(32M) Wl(2M) Wi(1.5M) Wo(0.5M) = 100MB.

typedef unsigned short u16;
typedef short s8v __attribute__((ext_vector_type(8)));   // 8 x bf16 (4 VGPR)
typedef float f4v __attribute__((ext_vector_type(4)));   // mfma accum
typedef unsigned short us8v __attribute__((ext_vector_type(8)));

typedef const __attribute__((address_space(1))) void* gas_t;
typedef __attribute__((address_space(3))) void* las_t;

__device__ __forceinline__ u16 f2bf(float f) {
  unsigned u = __builtin_bit_cast(unsigned, f);
  unsigned r = u + 0x7FFFu + ((u >> 16) & 1u);   // RNE
  return (u16)(r >> 16);
}

__device__ __forceinline__ void gload16(const void* g, void* l) {
  __builtin_amdgcn_global_load_lds((gas_t)g, (las_t)l, 16, 0, 0);
}

__global__ void cast_kernel(const float* __restrict__ in, u16* __restrict__ out, int n4) {
  int i = blockIdx.x * blockDim.x + threadIdx.x;
  const int stride = gridDim.x * blockDim.x;
  for (; i < n4; i += stride) {
    const float4 v = reinterpret_cast<const float4*>(in)[i];
    ushort4 o;
    o.x = f2bf(v.x); o.y = f2bf(v.y); o.z = f2bf(v.z); o.w = f2bf(v.w);
    reinterpret_cast<ushort4*>(out)[i] = o;
  }
}

// ---------------------------------------------------------------------------
// Generic 128x128-tile bf16 NT-GEMM: C = A(MxK) * B(NxK)^T + bias
// MODE 0: GEMM1  (K=1024) -> bf16 x_proj
// MODE 1: QKV    (K=256, per-head) -> Q/K [B,H,S,D] bf16, V transposed [B,H,D,S]
// MODE 2: outprj (K=256, per-head) -> fp32 d_out
// 4 waves; wave (wr,wc) owns 64x64; BK=64; LDS rows 128B, chunk^(row&7) swizzle.
// ---------------------------------------------------------------------------
template <int MODE>
__global__ void __launch_bounds__(256, 2) gemm128(
    const u16* __restrict__ A, const u16* __restrict__ Bw,
    const float* __restrict__ bias,
    u16* __restrict__ outB, float* __restrict__ outF,
    u16* __restrict__ Qo, u16* __restrict__ Ko, u16* __restrict__ Vo)
{
  constexpr int K    = (MODE == 0) ? 1024 : 256;
  constexpr int LDA  = 1024;
  constexpr int LDB  = (MODE == 0) ? 1024 : 256;
  constexpr int SMEM = (MODE == 1) ? 35072 : 32768;

  const int bx = blockIdx.x, ny = blockIdx.y, h = blockIdx.z;
  const int tid = threadIdx.x;
  const int wid = tid >> 6, l = tid & 63;
  const int l15 = l & 15, lg = l >> 4;
  const int wr = wid >> 1, wc = wid & 1;

  __shared__ __align__(16) char smem[SMEM];
  char* Al = smem;
  char* Bl = smem + 16384;

  const u16* Abase = A + (size_t)bx * 128 * LDA + ((MODE == 0) ? 0 : h * 256);
  const size_t bwoff = (MODE == 0) ? 0
                      : ((MODE == 1) ? (size_t)h * 768 * 256 : (size_t)h * 256 * 256);
  const u16* Bbase = Bw + bwoff + (size_t)ny * 128 * LDB;

  f4v acc[4][4];
#pragma unroll
  for (int i = 0; i < 4; ++i)
#pragma unroll
    for (int j = 0; j < 4; ++j) acc[i][j] = f4v{0.f, 0.f, 0.f, 0.f};

  for (int k0 = 0; k0 < K; k0 += 64) {
    __syncthreads();
#pragma unroll
    for (int ii = 0; ii < 4; ++ii) {             // A tile 128x64 -> 16KB
      const int i = wid * 4 + ii;
      const int row = i * 8 + (l >> 3);
      const int c = l & 7;
      gload16(Abase + (size_t)row * LDA + k0 + ((c ^ (row & 7)) << 3), Al + i * 1024);
    }
#pragma unroll
    for (int ii = 0; ii < 4; ++ii) {             // B tile 128x64 -> 16KB
      const int i = wid * 4 + ii;
      const int row = i * 8 + (l >> 3);
      const int c = l & 7;
      gload16(Bbase + (size_t)row * LDB + k0 + ((c ^ (row & 7)) << 3), Bl + i * 1024);
    }
    __syncthreads();
#pragma unroll
    for (int kf = 0; kf < 2; ++kf) {
      s8v a[4];
#pragma unroll
      for (int mf = 0; mf < 4; ++mf) {
        const int row = wr * 64 + mf * 16 + l15;
        a[mf] = *reinterpret_cast<const s8v*>(
            Al + row * 128 + (((kf * 32 + lg * 8) << 1) ^ ((row & 7) << 4)));
      }
#pragma unroll
      for (int nf = 0; nf < 4; ++nf) {
        const int n = wc * 64 + nf * 16 + l15;
        const s8v b = *reinterpret_cast<const s8v*>(
            Bl + n * 128 + (((kf * 32 + lg * 8) << 1) ^ ((n & 7) << 4)));
#pragma unroll
        for (int mf = 0; mf < 4; ++mf)
          acc[mf][nf] = __builtin_amdgcn_mfma_f32_16x16x32_bf16(a[mf], b, acc[mf][nf], 0, 0, 0);
      }
    }
  }

  const int mbase = bx * 128 + wr * 64;
  const int nbase = ny * 128 + wc * 64;

  if constexpr (MODE == 0) {
#pragma unroll
    for (int nf = 0; nf < 4; ++nf) {
      const int colg = nbase + nf * 16 + l15;
      const float bv = bias[colg];
#pragma unroll
      for (int mf = 0; mf < 4; ++mf)
#pragma unroll
        for (int r = 0; r < 4; ++r) {
          const int mr = mbase + mf * 16 + lg * 4 + r;
          outB[(size_t)mr * 1024 + colg] = f2bf(acc[mf][nf][r] + bv);
        }
    }
  } else if constexpr (MODE == 2) {
#pragma unroll
    for (int nf = 0; nf < 4; ++nf) {
      const int colg = nbase + nf * 16 + l15;
      const float bv = bias[h * 256 + colg];
#pragma unroll
      for (int mf = 0; mf < 4; ++mf)
#pragma unroll
        for (int r = 0; r < 4; ++r) {
          const int mr = mbase + mf * 16 + lg * 4 + r;
          outF[(size_t)mr * 1024 + h * 256 + colg] = acc[mf][nf][r] + bv;
        }
    }
  } else {  // MODE 1: QKV
    if (ny < 4) {                                // Q (ny 0,1) / K (ny 2,3)
      u16* dst = (ny < 2) ? Qo : Ko;
      const int cb = (ny < 2) ? 0 : 256;
#pragma unroll
      for (int nf = 0; nf < 4; ++nf) {
        const int colg = nbase + nf * 16 + l15;
        const float bv = bias[h * 768 + colg];
        const int d = colg - cb;
#pragma unroll
        for (int mf = 0; mf < 4; ++mf)
#pragma unroll
          for (int r = 0; r < 4; ++r) {
            const int mr = mbase + mf * 16 + lg * 4 + r;
            const int b = mr >> 11, s = mr & 2047;
            dst[((size_t)(b * 4 + h) * 2048 + s) * 256 + d] = f2bf(acc[mf][nf][r] + bv);
          }
      }
    } else {                                     // V (ny 4,5): transpose via LDS
      __syncthreads();                           // staging LDS reads done
      short* tr = reinterpret_cast<short*>(smem);
#pragma unroll
      for (int nf = 0; nf < 4; ++nf) {
        const int colg = nbase + nf * 16 + l15;
        const float bv = bias[h * 768 + colg];
        const int cl = wc * 64 + nf * 16 + l15;
#pragma unroll
        for (int mf = 0; mf < 4; ++mf)
#pragma unroll
          for (int r = 0; r < 4; ++r) {
            const int rl = wr * 64 + mf * 16 + lg * 4 + r;
            tr[rl * 137 + cl] = (short)f2bf(acc[mf][nf][r] + bv);   // pad 137: 2-way banks
          }
      }
      __syncthreads();
      const int b = bx >> 4;
      const int sbase = (bx & 15) * 128;
#pragma unroll
      for (int rep = 0; rep < 8; ++rep) {
        const int u = rep * 256 + tid;
        const int d = u >> 4, sb = u & 15;
        us8v v;
#pragma unroll
        for (int j = 0; j < 8; ++j) v[j] = (u16)tr[(sb * 8 + j) * 137 + d];
        *reinterpret_cast<us8v*>(
            Vo + ((size_t)(b * 4 + h) * 256 + (ny - 4) * 128 + d) * 2048 + sbase + sb * 8) = v;
      }
    }
  }
}

// ---------------------------------------------------------------------------
// Flash attention. Grid (S/64, B*H). 4 waves; wave owns 16 q-rows x D=256.
// K tile [64][256] + Vt tile [256][64] in LDS (chunk^(row&7) swizzle),
// Q hoisted to registers, online softmax, P via padded per-wave LDS.
// ---------------------------------------------------------------------------
__global__ void __launch_bounds__(256, 2) attn_fwd(
    const u16* __restrict__ Q, const u16* __restrict__ Kk,
    const u16* __restrict__ Vt, u16* __restrict__ AO)
{
  const int bh = blockIdx.y;
  const int qt = blockIdx.x;
  const int tid = threadIdx.x;
  const int wid = tid >> 6, l = tid & 63;
  const int l15 = l & 15, lg = l >> 4;

  __shared__ __align__(16) char smem[32768 + 32768 + 9216];
  char* Kl = smem;
  char* Vl = smem + 32768;
  short* Pl = reinterpret_cast<short*>(smem + 65536) + wid * 1152;   // 16 x (64+8)

  s8v qa[8];
  {
    const u16* qrow = Q + ((size_t)bh * 2048 + qt * 64 + wid * 16 + l15) * 256;
#pragma unroll
    for (int kf = 0; kf < 8; ++kf)
      qa[kf] = *reinterpret_cast<const s8v*>(qrow + kf * 32 + lg * 8);
  }

  f4v O[16];
#pragma unroll
  for (int i = 0; i < 16; ++i) O[i] = f4v{0.f, 0.f, 0.f, 0.f};
  float m_run[4] = {-3e38f, -3e38f, -3e38f, -3e38f};
  float l_run[4] = {0.f, 0.f, 0.f, 0.f};

  const size_t kbase = (size_t)bh * 2048 * 256;
  const size_t vbase = (size_t)bh * 256 * 2048;

  for (int t0 = 0; t0 < 2048; t0 += 64) {
    __syncthreads();                              // prev tile's LDS reads done
#pragma unroll
    for (int ii = 0; ii < 8; ++ii) {              // K tile: rows 512B
      const int i = wid * 8 + ii;
      const int row = i * 2 + (l >> 5);
      const int c = l & 31;
      gload16(Kk + kbase + (size_t)(t0 + row) * 256 + ((c ^ (row & 7)) << 3), Kl + i * 1024);
    }
#pragma unroll
    for (int ii = 0; ii < 8; ++ii) {              // Vt tile: rows 128B
      const int i = wid * 8 + ii;
      const int d = i * 8 + (l >> 3);
      const int c = l & 7;
      gload16(Vt + vbase + (size_t)d * 2048 + t0 + ((c ^ (d & 7)) << 3), Vl + i * 1024);
    }
    __syncthreads();

    f4v S[4];
#pragma unroll
    for (int i = 0; i < 4; ++i) S[i] = f4v{0.f, 0.f, 0.f, 0.f};
#pragma unroll
    for (int kf = 0; kf < 8; ++kf) {
#pragma unroll
      for (int nf = 0; nf < 4; ++nf) {
        const int tl = nf * 16 + l15;
        const s8v kb = *reinterpret_cast<const s8v*>(
            Kl + tl * 512 + (((kf * 32 + lg * 8) << 1) ^ ((tl & 7) << 4)));
        S[nf] = __builtin_amdgcn_mfma_f32_16x16x32_bf16(qa[kf], kb, S[nf], 0, 0, 0);
      }
    }

    float fac[4];
#pragma unroll
    for (int r = 0; r < 4; ++r) {                 // row = lg*4 + r
      const float s0 = S[0][r] * 0.0625f;
      const float s1 = S[1][r] * 0.0625f;
      const float s2 = S[2][r] * 0.0625f;
      const float s3 = S[3][r] * 0.0625f;
      float mx = fmaxf(fmaxf(s0, s1), fmaxf(s2, s3));
      mx = fmaxf(mx, __shfl_xor(mx, 1));
      mx = fmaxf(mx, __shfl_xor(mx, 2));
      mx = fmaxf(mx, __shfl_xor(mx, 4));
      mx = fmaxf(mx, __shfl_xor(mx, 8));
      const float m_new = fmaxf(m_run[r], mx);
      fac[r] = __expf(m_run[r] - m_new);
      m_run[r] = m_new;
      const float p0 = __expf(s0 - m_new);
      const float p1 = __expf(s1 - m_new);
      const float p2 = __expf(s2 - m_new);
      const float p3 = __expf(s3 - m_new);
      float rs = p0 + p1 + p2 + p3;
      rs += __shfl_xor(rs, 1);
      rs += __shfl_xor(rs, 2);
      rs += __shfl_xor(rs, 4);
      rs += __shfl_xor(rs, 8);
      l_run[r] = l_run[r] * fac[r] + rs;
      short* pr = Pl + (lg * 4 + r) * 72;
      pr[l15]      = (short)f2bf(p0);
      pr[16 + l15] = (short)f2bf(p1);
      pr[32 + l15] = (short)f2bf(p2);
      pr[48 + l15] = (short)f2bf(p3);
    }

#pragma unroll
    for (int df = 0; df < 16; ++df) {             // rescale O
      O[df][0] *= fac[0]; O[df][1] *= fac[1];
      O[df][2] *= fac[2]; O[df][3] *= fac[3];
    }

    __syncthreads();                              // cross-lane P visibility

    s8v pa[2];
#pragma unroll
    for (int kf2 = 0; kf2 < 2; ++kf2)
      pa[kf2] = *reinterpret_cast<const s8v*>(Pl + l15 * 72 + kf2 * 32 + lg * 8);

#pragma unroll
    for (int kf2 = 0; kf2 < 2; ++kf2) {
#pragma unroll
      for (int df = 0; df < 16; ++df) {
        const int dl = df * 16 + l15;
        const s8v vb = *reinterpret_cast<const s8v*>(
            Vl + dl * 128 + (((kf2 * 32 + lg * 8) << 1) ^ ((dl & 7) << 4)));
        O[df] = __builtin_amdgcn_mfma_f32_16x16x32_bf16(pa[kf2], vb, O[df], 0, 0, 0);
      }
    }
  }

  float inv[4];
#pragma unroll
  for (int r = 0; r < 4; ++r) inv[r] = 1.0f / l_run[r];
  const int b = bh >> 2, h = bh & 3;
#pragma unroll
  for (int df = 0; df < 16; ++df)
#pragma unroll
    for (int r = 0; r < 4; ++r) {
      const int srow = qt * 64 + wid * 16 + lg * 4 + r;
      AO[(size_t)(b * 2048 + srow) * 1024 + h * 256 + df * 16 + l15] = f2bf(O[df][r] * inv[r]);
    }
}

// ---------------------------------------------------------------------------
extern "C" void kernel_launch(void* const* d_in, const int* in_sizes, int n_in,
                              void* d_out, int out_size, void* d_ws, size_t ws_size,
                              hipStream_t stream) {
  (void)in_sizes; (void)n_in; (void)out_size; (void)ws_size;
  const float* x     = (const float*)d_in[0];
  const float* W_lin = (const float*)d_in[1];
  const float* b_lin = (const float*)d_in[2];
  const float* W_in  = (const float*)d_in[3];
  const float* b_in  = (const float*)d_in[4];
  const float* W_out = (const float*)d_in[5];
  const float* b_out = (const float*)d_in[6];

  char* ws = (char*)d_ws;
  u16* Qb  = (u16*)(ws);                               // 32 MB [B,H,S,D]
  u16* Vtb = (u16*)(ws + (32ull << 20));               // 32 MB [B,H,D,S]
  u16* AOb = (u16*)(ws + (64ull << 20));               // 32 MB [B,S,E]
  u16* WLb = (u16*)(ws + (96ull << 20));               // 2 MB
  u16* WIb = (u16*)(ws + (98ull << 20));               // 1.5 MB
  u16* WOb = (u16*)(ws + (98ull << 20) + 1572864ull);  // 0.5 MB

  char* doc  = (char*)d_out;
  u16* xb    = (u16*)doc;                    // 32 MB, dead after gemm<0>
  u16* xproj = (u16*)(doc + (32ull << 20));  // 32 MB, dead after gemm<1>
  u16* Kb    = (u16*)doc;                    // K reuses xb region [B,H,S,D]
  float* outF = (float*)d_out;

  cast_kernel<<<2048, 256, 0, stream>>>(x, xb, 4194304);
  cast_kernel<<<1024, 256, 0, stream>>>(W_lin, WLb, 262144);
  cast_kernel<<<768, 256, 0, stream>>>(W_in, WIb, 196608);
  cast_kernel<<<256, 256, 0, stream>>>(W_out, WOb, 65536);

  gemm128<0><<<dim3(128, 8, 1), 256, 0, stream>>>(xb, WLb, b_lin, xproj, nullptr,
                                                  nullptr, nullptr, nullptr);
  gemm128<1><<<dim3(128, 6, 4), 256, 0, stream>>>(xproj, WIb, b_in, nullptr, nullptr,
                                                  Qb, Kb, Vtb);
  attn_fwd<<<dim3(32, 32, 1), 256, 0, stream>>>(Qb, Kb, Vtb, AOb);
  gemm128<2><<<dim3(128, 2, 4), 256, 0, stream>>>(AOb, WOb, b_out, nullptr, outF,
                                                  nullptr, nullptr, nullptr);
}